// Round 5
// baseline (123.358 us; speedup 1.0000x reference)
//
#include <hip/hip_runtime.h>
#include <hip/hip_bf16.h>

// Problem constants (B,C,T,H,W = 2,64,8,48,48)
#define CC 64
#define TT 8
#define PP 2304        // 48*48
#define C2 32
#define BT 16          // B*T
#define NKT 36         // key tiles of 64
#define QKT 9          // records per key-group (4-way split)
// log2(e)/sqrt(32): folds softmax scale AND exp->exp2 into theta pre-scale
#define SCALE2 0.25503486f

using h8 = __attribute__((ext_vector_type(8))) _Float16;  // 4 VGPRs
using h4 = __attribute__((ext_vector_type(4))) _Float16;  // 2 VGPRs
using f4 = __attribute__((ext_vector_type(4))) float;     // MFMA C/D frag

#if __has_builtin(__builtin_amdgcn_exp2f)
#define EXP2(v) __builtin_amdgcn_exp2f(v)
#else
#define EXP2(v) exp2f(v)
#endif

// XCD swizzle: dispatch round-robins XCDs by linear block id; fixing
// blockIdx.x per bt puts all consumers of one bt on ONE XCD whose 4 MB L2
// holds that bt's ~870 KB record set. k_prep uses the same map so records
// are produced on the consuming XCD. Perf heuristic only.
#define SWIZ_BT(xcd, g) ((xcd) + 8 * ((g) & 1))
#define SWIZ_PT(g) ((g) >> 1)

// Workspace (_Float16):
//  thf[bt][g16 (144 of 16p)][lane][8]   theta B-frags (pre-scaled)  2.25 MB
//  rec[bt][kt] = 12 KB record:                                      7.08 MB
//     halves [0,2048):  phi A-frags   [nt(4)][lane][8]
//     halves [2048,6144): x PV A-frags [g(2)][ct(4)][lane][8], packed in the
//       K=32 key-permuted order: slot k=quad*8+j holds key
//       32g + (j<4 ? quad*4+j : 16+quad*4+(j-4)).  With this order the PV
//       B-operand is just the concat of two S D-frag h4's -> full-rate
//       16x16x32 PV MFMAs with zero cross-lane traffic.
// Every k_attn load is base + lane*16B: fully coalesced dwordx4 from L2.

// ---------------------------------------------------------------------------
// k_prep: grid (8, 72), 256 thr. Coalesced x patch -> LDS (transposed),
// MFMA theta/phi projections, emit thf + per-kt combined frag records.
// (Unchanged from the last passing round.)
// ---------------------------------------------------------------------------
__global__ __launch_bounds__(256) void k_prep(
    const float* __restrict__ x, const float* __restrict__ tw,
    const float* __restrict__ pw, _Float16* __restrict__ thf,
    _Float16* __restrict__ rec) {
  const int qt = SWIZ_PT(blockIdx.y), bt = SWIZ_BT(blockIdx.x, blockIdx.y);
  const int b = bt >> 3, t = bt & 7;
  const int tid = threadIdx.x;
  const int wv = tid >> 6, lane = tid & 63;
  const int quad = lane >> 4, l15 = lane & 15;

  __shared__ __align__(16) float x_s[64][68];         // [q_loc][c]
  __shared__ __align__(16) _Float16 th_s[4][16][32];  // per-wave [q16][c2]
  __shared__ __align__(16) _Float16 ph_s[4][16][32];

  const size_t xslice = ((size_t)b * CC * TT + t) * PP;
  const int qg0 = qt * 64;

  // stage x patch (64c x 64q) transposed to [q][c]; float4 along q
  {
    const int l16 = tid & 15;
    const int crow = tid >> 4;  // 16 c rows per pass
#pragma unroll
    for (int ppass = 0; ppass < 4; ppass++) {
      const int c = ppass * 16 + crow;
      float4 u = *reinterpret_cast<const float4*>(
          &x[xslice + (size_t)c * (TT * PP) + qg0 + l16 * 4]);
      x_s[l16 * 4 + 0][c] = u.x;
      x_s[l16 * 4 + 1][c] = u.y;
      x_s[l16 * 4 + 2][c] = u.z;
      x_s[l16 * 4 + 3][c] = u.w;
    }
  }
  __syncthreads();

  // projections: D[m=c2][n=q_loc] = W[c2][c] . x[q_loc][c], K=64
  h8 bx[2];
#pragma unroll
  for (int ks = 0; ks < 2; ks++) {
    const float* row = &x_s[wv * 16 + l15][ks * 32 + quad * 8];
    float4 u0 = *reinterpret_cast<const float4*>(row);
    float4 u1 = *reinterpret_cast<const float4*>(row + 4);
    bx[ks][0] = (_Float16)u0.x; bx[ks][1] = (_Float16)u0.y;
    bx[ks][2] = (_Float16)u0.z; bx[ks][3] = (_Float16)u0.w;
    bx[ks][4] = (_Float16)u1.x; bx[ks][5] = (_Float16)u1.y;
    bx[ks][6] = (_Float16)u1.z; bx[ks][7] = (_Float16)u1.w;
  }

  const float* twt = tw + t * C2 * CC;
  const float* pwt = pw + t * C2 * CC;
  const f4 zero = {0.f, 0.f, 0.f, 0.f};
  f4 accT[2] = {zero, zero}, accP[2] = {zero, zero};
#pragma unroll
  for (int mt = 0; mt < 2; mt++)
#pragma unroll
    for (int ks = 0; ks < 2; ks++) {
      const float* wr = twt + (mt * 16 + l15) * CC + ks * 32 + quad * 8;
      const float* pr = pwt + (mt * 16 + l15) * CC + ks * 32 + quad * 8;
      float4 a0 = *reinterpret_cast<const float4*>(wr);
      float4 a1 = *reinterpret_cast<const float4*>(wr + 4);
      float4 p0 = *reinterpret_cast<const float4*>(pr);
      float4 p1 = *reinterpret_cast<const float4*>(pr + 4);
      h8 at = {(_Float16)a0.x, (_Float16)a0.y, (_Float16)a0.z, (_Float16)a0.w,
               (_Float16)a1.x, (_Float16)a1.y, (_Float16)a1.z, (_Float16)a1.w};
      h8 ap = {(_Float16)p0.x, (_Float16)p0.y, (_Float16)p0.z, (_Float16)p0.w,
               (_Float16)p1.x, (_Float16)p1.y, (_Float16)p1.z, (_Float16)p1.w};
      accT[mt] =
          __builtin_amdgcn_mfma_f32_16x16x32_f16(at, bx[ks], accT[mt], 0, 0, 0);
      accP[mt] =
          __builtin_amdgcn_mfma_f32_16x16x32_f16(ap, bx[ks], accP[mt], 0, 0, 0);
    }

  // D -> per-wave slab: lane = col q_loc=l15, rows c2 = mt*16+quad*4+r
#pragma unroll
  for (int mt = 0; mt < 2; mt++) {
    h4 tv, pv;
#pragma unroll
    for (int r = 0; r < 4; r++) {
      tv[r] = (_Float16)(accT[mt][r] * SCALE2);
      pv[r] = (_Float16)accP[mt][r];
    }
    *reinterpret_cast<h4*>(&th_s[wv][l15][mt * 16 + quad * 4]) = tv;
    *reinterpret_cast<h4*>(&ph_s[wv][l15][mt * 16 + quad * 4]) = pv;
  }
  // same-wave ds write->read ordering suffices

  // theta B-frags out
  h8 tfrag = *reinterpret_cast<const h8*>(&th_s[wv][l15][quad * 8]);
  *reinterpret_cast<h8*>(
      thf + (((size_t)(bt * NKT + qt) * 4 + wv) * 64 + lane) * 8) = tfrag;

  // combined record: phi chunk wv, then key-permuted x chunks
  _Float16* rb = rec + (size_t)(bt * NKT + qt) * 6144;
  h8 pfrag = *reinterpret_cast<const h8*>(&ph_s[wv][l15][quad * 8]);
  *reinterpret_cast<h8*>(rb + wv * 512 + lane * 8) = pfrag;

  // x chunks (g,ct): wave wv owns g=wv>>1, ct=(wv&1)*2+{0,1}.
  // slot j<4 -> key 32g+quad*4+j ; j>=4 -> key 32g+16+quad*4+(j-4)
  {
    const int g = wv >> 1;
#pragma unroll
    for (int ct2 = 0; ct2 < 2; ct2++) {
      const int ct = (wv & 1) * 2 + ct2;
      h8 v;
#pragma unroll
      for (int j = 0; j < 4; j++) {
        v[j] = (_Float16)x_s[32 * g + quad * 4 + j][ct * 16 + l15];
        v[4 + j] = (_Float16)x_s[32 * g + 16 + quad * 4 + j][ct * 16 + l15];
      }
      *reinterpret_cast<h8*>(rb + 2048 + (g * 4 + ct) * 512 + lane * 8) = v;
    }
  }
}

// ---------------------------------------------------------------------------
// k_attn: grid (8, 36), 512 thr = 8 waves = 2 p-strips(64) x 4 key-groups.
// Per-wave math identical to the last passing round (W=64, register-only
// main loop, full-rate 16x16x32 PV). New: the two same-kg waves (strip 0/1)
// walk IDENTICAL record sequences in lockstep on one CU -> L1 dedup halves
// the record traffic leaving each CU (~249 -> ~127 MB device-wide). The
// epilogue serializes the two strips through one 68 KB exchange buffer with
// uniform barriers.
// ---------------------------------------------------------------------------
__global__ __launch_bounds__(512, 2) void k_attn(
    const float* __restrict__ x, const _Float16* __restrict__ thf,
    const _Float16* __restrict__ rec, const float* __restrict__ ow,
    float* __restrict__ out) {
  const int sp = SWIZ_PT(blockIdx.y);  // [0,18), 128 p each
  const int bt = SWIZ_BT(blockIdx.x, blockIdx.y);
  const int b = bt >> 3, t = bt & 7;
  const int tid = threadIdx.x;
  const int wv = tid >> 6, lane = tid & 63;
  const int st = wv >> 2, kg = wv & 3;  // strip-half, key-group
  const int quad = lane >> 4, l15 = lane & 15;
  const int strip = sp * 2 + st;  // [0,36), 64 p each

  __shared__ __align__(16) float exch[4 * 4 * 16 * 64];  // 64 KB (per phase)
  __shared__ float exl[4 * 4 * 64];                      // 4 KB

  // theta B-frags for this strip's four 16-col groups
  h8 bth[4];
#pragma unroll
  for (int pf = 0; pf < 4; pf++)
    bth[pf] = *reinterpret_cast<const h8*>(
        thf + (((size_t)bt * 144 + strip * 4 + pf) * 64 + lane) * 8);

  const _Float16* recb =
      rec + ((size_t)bt * NKT + (size_t)kg * QKT) * 6144 + lane * 8;

  const f4 zero = {0.f, 0.f, 0.f, 0.f};
  f4 O[4][4];  // [ct][pf]: rows c=ct*16+quad*4+r, col p=strip*64+pf*16+l15
#pragma unroll
  for (int ct = 0; ct < 4; ct++)
#pragma unroll
    for (int pf = 0; pf < 4; pf++) O[ct][pf] = zero;
  float lsum[4] = {0.f, 0.f, 0.f, 0.f};

  h8 Abuf[12], Bbuf[12];  // [0..3] phi A-frags, [4..11] x A-frags (g*4+ct)

#define LOADREC(BUF, kt)                                          \
  {                                                               \
    const _Float16* _p = recb + (size_t)(kt)*6144;                \
    _Pragma("unroll") for (int j = 0; j < 12; j++)                \
        BUF[j] = *reinterpret_cast<const h8*>(_p + j * 512);      \
  }

// pf-sequential: s[] transient per pf keeps VGPR down (O 64 + dbuf 96 + ...)
#define COMPUTE(BUF)                                                          \
  {                                                                           \
    _Pragma("unroll") for (int pf = 0; pf < 4; pf++) {                        \
      f4 s[4];                                                                \
      _Pragma("unroll") for (int nt = 0; nt < 4; nt++)                        \
          s[nt] = __builtin_amdgcn_mfma_f32_16x16x32_f16(BUF[nt], bth[pf],    \
                                                         zero, 0, 0, 0);     \
      _Pragma("unroll") for (int g = 0; g < 2; g++) {                         \
        h8 bw;                                                                \
        _Pragma("unroll") for (int r = 0; r < 4; r++) {                       \
          float w0 = EXP2(s[2 * g][r]);                                       \
          float w1 = EXP2(s[2 * g + 1][r]);                                   \
          lsum[pf] += w0 + w1;                                                \
          bw[r] = (_Float16)w0;                                               \
          bw[4 + r] = (_Float16)w1;                                           \
        }                                                                     \
        _Pragma("unroll") for (int ct = 0; ct < 4; ct++)                      \
            O[ct][pf] = __builtin_amdgcn_mfma_f32_16x16x32_f16(               \
                BUF[4 + g * 4 + ct], bw, O[ct][pf], 0, 0, 0);                 \
      }                                                                       \
    }                                                                         \
  }

  LOADREC(Abuf, 0);
#pragma unroll 1
  for (int i = 0; i < QKT - 1; i += 2) {
    LOADREC(Bbuf, i + 1);
    COMPUTE(Abuf);
    LOADREC(Abuf, i + 2);
    COMPUTE(Bbuf);
  }
  COMPUTE(Abuf);  // record 8
#undef LOADREC
#undef COMPUTE

  // partial denominators: combine quad groups (p = pf*16+l15 fixed)
#pragma unroll
  for (int pf = 0; pf < 4; pf++) {
    lsum[pf] += __shfl_xor(lsum[pf], 16);
    lsum[pf] += __shfl_xor(lsum[pf], 32);
  }

  // epilogue: strips take turns using the exchange buffer (uniform barriers)
#pragma unroll 1
  for (int phase = 0; phase < 2; phase++) {
    __syncthreads();  // prior phase's reads done before overwrite
    if (st == phase) {
#pragma unroll
      for (int pf = 0; pf < 4; pf++) {
#pragma unroll
        for (int ct = 0; ct < 4; ct++)
#pragma unroll
          for (int r = 0; r < 4; r++)
            exch[((kg * 4 + pf) * 16 + ct * 4 + r) * 64 + lane] = O[ct][pf][r];
        exl[(kg * 4 + pf) * 64 + lane] = lsum[pf];
      }
    }
    __syncthreads();
    if (st == phase) {
      float ls = 0.f;
#pragma unroll
      for (int src = 0; src < 4; src++) ls += exl[(src * 4 + kg) * 64 + lane];
      const float inv = 1.f / ls;

      // f in B-frag layout for out-proj: B[k=c=ct*16+quad*4+r][n=p=l15]
      h4 bf[4];
#pragma unroll
      for (int ct = 0; ct < 4; ct++)
#pragma unroll
        for (int r = 0; r < 4; r++) {
          float acc = 0.f;
#pragma unroll
          for (int src = 0; src < 4; src++)
            acc += exch[((src * 4 + kg) * 16 + ct * 4 + r) * 64 + lane];
          bf[ct][r] = (_Float16)(acc * inv);
        }

      f4 D3[4] = {zero, zero, zero, zero};
#pragma unroll
      for (int mt = 0; mt < 4; mt++)
#pragma unroll
        for (int ct = 0; ct < 4; ct++) {
          const float* wrow =
              ow + (size_t)(mt * 16 + l15) * CC + ct * 16 + quad * 4;
          float4 u = *reinterpret_cast<const float4*>(wrow);
          h4 aw = {(_Float16)u.x, (_Float16)u.y, (_Float16)u.z, (_Float16)u.w};
          D3[mt] =
              __builtin_amdgcn_mfma_f32_16x16x16f16(aw, bf[ct], D3[mt], 0, 0, 0);
        }

      // stores with fp32 residual; wave kg owns p block strip*64 + kg*16
      const int p0 = strip * 64 + kg * 16 + l15;
#pragma unroll
      for (int mt = 0; mt < 4; mt++)
#pragma unroll
        for (int r = 0; r < 4; r++) {
          const int o = mt * 16 + quad * 4 + r;
          const size_t base = ((size_t)(b * CC + o) * TT + t) * PP + p0;
          out[base] = D3[mt][r] + x[base];
        }
    }
  }
}

extern "C" void kernel_launch(void* const* d_in, const int* in_sizes, int n_in,
                              void* d_out, int out_size, void* d_ws,
                              size_t ws_size, hipStream_t stream) {
  (void)in_sizes; (void)n_in; (void)out_size; (void)ws_size;
  const float* x = (const float*)d_in[0];
  const float* tw = (const float*)d_in[1];
  const float* pw = (const float*)d_in[2];
  const float* ow = (const float*)d_in[3];
  float* out = (float*)d_out;

  _Float16* thf = (_Float16*)d_ws;                      // 2.25 MB
  _Float16* rec = thf + (size_t)BT * NKT * 4 * 64 * 8;  // 7.08 MB

  k_prep<<<dim3(8, 72), 256, 0, stream>>>(x, tw, pw, thf, rec);
  k_attn<<<dim3(8, 36), 512, 0, stream>>>(x, thf, rec, ow, out);
}

// Round 6
// 98.555 us; speedup vs baseline: 1.2517x; 1.2517x over previous
//
#include <hip/hip_runtime.h>
#include <hip/hip_bf16.h>

// Problem constants (B,C,T,H,W = 2,64,8,48,48)
#define CC 64
#define TT 8
#define PP 2304        // 48*48
#define C2 32
#define BT 16          // B*T
#define NKT 36         // key tiles of 64
#define QKT 9          // records per key-group (4-way split)
// log2(e)/sqrt(32): folds softmax scale AND exp->exp2 into theta pre-scale
#define SCALE2 0.25503486f

using h8 = __attribute__((ext_vector_type(8))) _Float16;  // 4 VGPRs
using h4 = __attribute__((ext_vector_type(4))) _Float16;  // 2 VGPRs
using f4 = __attribute__((ext_vector_type(4))) float;     // MFMA C/D frag

#if __has_builtin(__builtin_amdgcn_exp2f)
#define EXP2(v) __builtin_amdgcn_exp2f(v)
#else
#define EXP2(v) exp2f(v)
#endif

// XCD swizzle: dispatch round-robins XCDs by linear block id; fixing
// blockIdx.x per bt puts all consumers of one bt on ONE XCD whose 4 MB L2
// holds that bt's ~870 KB record set. k_prep uses the same map so records
// are produced on the consuming XCD. Perf heuristic only.
#define SWIZ_BT(xcd, g) ((xcd) + 8 * ((g) & 1))

// Workspace (_Float16):
//  thf[bt][g16 (144 of 16p)][lane][8]   theta B-frags (pre-scaled)  2.25 MB
//  rec[bt][kt] = 12 KB record:                                      7.08 MB
//     halves [0,2048):  phi A-frags   [nt(4)][lane][8]
//     halves [2048,6144): x PV A-frags [g(2)][ct(4)][lane][8], packed in the
//       K=32 key-permuted order: slot k=quad*8+j holds key
//       32g + (j<4 ? quad*4+j : 16+quad*4+(j-4)).  With this order the PV
//       B-operand is just the concat of two S D-frag h4's -> full-rate
//       16x16x32 PV MFMAs with zero cross-lane traffic.
// Every k_attn load is base + lane*16B: fully coalesced dwordx4 from L2.

// ---------------------------------------------------------------------------
// k_prep: grid (8, 72), 256 thr. Coalesced x patch -> LDS (transposed),
// MFMA theta/phi projections, emit thf + per-kt combined frag records.
// (Unchanged from the last passing round.)
// ---------------------------------------------------------------------------
__global__ __launch_bounds__(256) void k_prep(
    const float* __restrict__ x, const float* __restrict__ tw,
    const float* __restrict__ pw, _Float16* __restrict__ thf,
    _Float16* __restrict__ rec) {
  const int qt = blockIdx.y >> 1, bt = SWIZ_BT(blockIdx.x, blockIdx.y);
  const int b = bt >> 3, t = bt & 7;
  const int tid = threadIdx.x;
  const int wv = tid >> 6, lane = tid & 63;
  const int quad = lane >> 4, l15 = lane & 15;

  __shared__ __align__(16) float x_s[64][68];         // [q_loc][c]
  __shared__ __align__(16) _Float16 th_s[4][16][32];  // per-wave [q16][c2]
  __shared__ __align__(16) _Float16 ph_s[4][16][32];

  const size_t xslice = ((size_t)b * CC * TT + t) * PP;
  const int qg0 = qt * 64;

  // stage x patch (64c x 64q) transposed to [q][c]; float4 along q
  {
    const int l16 = tid & 15;
    const int crow = tid >> 4;  // 16 c rows per pass
#pragma unroll
    for (int ppass = 0; ppass < 4; ppass++) {
      const int c = ppass * 16 + crow;
      float4 u = *reinterpret_cast<const float4*>(
          &x[xslice + (size_t)c * (TT * PP) + qg0 + l16 * 4]);
      x_s[l16 * 4 + 0][c] = u.x;
      x_s[l16 * 4 + 1][c] = u.y;
      x_s[l16 * 4 + 2][c] = u.z;
      x_s[l16 * 4 + 3][c] = u.w;
    }
  }
  __syncthreads();

  // projections: D[m=c2][n=q_loc] = W[c2][c] . x[q_loc][c], K=64
  h8 bx[2];
#pragma unroll
  for (int ks = 0; ks < 2; ks++) {
    const float* row = &x_s[wv * 16 + l15][ks * 32 + quad * 8];
    float4 u0 = *reinterpret_cast<const float4*>(row);
    float4 u1 = *reinterpret_cast<const float4*>(row + 4);
    bx[ks][0] = (_Float16)u0.x; bx[ks][1] = (_Float16)u0.y;
    bx[ks][2] = (_Float16)u0.z; bx[ks][3] = (_Float16)u0.w;
    bx[ks][4] = (_Float16)u1.x; bx[ks][5] = (_Float16)u1.y;
    bx[ks][6] = (_Float16)u1.z; bx[ks][7] = (_Float16)u1.w;
  }

  const float* twt = tw + t * C2 * CC;
  const float* pwt = pw + t * C2 * CC;
  const f4 zero = {0.f, 0.f, 0.f, 0.f};
  f4 accT[2] = {zero, zero}, accP[2] = {zero, zero};
#pragma unroll
  for (int mt = 0; mt < 2; mt++)
#pragma unroll
    for (int ks = 0; ks < 2; ks++) {
      const float* wr = twt + (mt * 16 + l15) * CC + ks * 32 + quad * 8;
      const float* pr = pwt + (mt * 16 + l15) * CC + ks * 32 + quad * 8;
      float4 a0 = *reinterpret_cast<const float4*>(wr);
      float4 a1 = *reinterpret_cast<const float4*>(wr + 4);
      float4 p0 = *reinterpret_cast<const float4*>(pr);
      float4 p1 = *reinterpret_cast<const float4*>(pr + 4);
      h8 at = {(_Float16)a0.x, (_Float16)a0.y, (_Float16)a0.z, (_Float16)a0.w,
               (_Float16)a1.x, (_Float16)a1.y, (_Float16)a1.z, (_Float16)a1.w};
      h8 ap = {(_Float16)p0.x, (_Float16)p0.y, (_Float16)p0.z, (_Float16)p0.w,
               (_Float16)p1.x, (_Float16)p1.y, (_Float16)p1.z, (_Float16)p1.w};
      accT[mt] =
          __builtin_amdgcn_mfma_f32_16x16x32_f16(at, bx[ks], accT[mt], 0, 0, 0);
      accP[mt] =
          __builtin_amdgcn_mfma_f32_16x16x32_f16(ap, bx[ks], accP[mt], 0, 0, 0);
    }

  // D -> per-wave slab: lane = col q_loc=l15, rows c2 = mt*16+quad*4+r
#pragma unroll
  for (int mt = 0; mt < 2; mt++) {
    h4 tv, pv;
#pragma unroll
    for (int r = 0; r < 4; r++) {
      tv[r] = (_Float16)(accT[mt][r] * SCALE2);
      pv[r] = (_Float16)accP[mt][r];
    }
    *reinterpret_cast<h4*>(&th_s[wv][l15][mt * 16 + quad * 4]) = tv;
    *reinterpret_cast<h4*>(&ph_s[wv][l15][mt * 16 + quad * 4]) = pv;
  }
  // same-wave ds write->read ordering suffices

  // theta B-frags out
  h8 tfrag = *reinterpret_cast<const h8*>(&th_s[wv][l15][quad * 8]);
  *reinterpret_cast<h8*>(
      thf + (((size_t)(bt * NKT + qt) * 4 + wv) * 64 + lane) * 8) = tfrag;

  // combined record: phi chunk wv, then key-permuted x chunks
  _Float16* rb = rec + (size_t)(bt * NKT + qt) * 6144;
  h8 pfrag = *reinterpret_cast<const h8*>(&ph_s[wv][l15][quad * 8]);
  *reinterpret_cast<h8*>(rb + wv * 512 + lane * 8) = pfrag;

  // x chunks (g,ct): wave wv owns g=wv>>1, ct=(wv&1)*2+{0,1}.
  // slot j<4 -> key 32g+quad*4+j ; j>=4 -> key 32g+16+quad*4+(j-4)
  {
    const int g = wv >> 1;
#pragma unroll
    for (int ct2 = 0; ct2 < 2; ct2++) {
      const int ct = (wv & 1) * 2 + ct2;
      h8 v;
#pragma unroll
      for (int j = 0; j < 4; j++) {
        v[j] = (_Float16)x_s[32 * g + quad * 4 + j][ct * 16 + l15];
        v[4 + j] = (_Float16)x_s[32 * g + 16 + quad * 4 + j][ct * 16 + l15];
      }
      *reinterpret_cast<h8*>(rb + 2048 + (g * 4 + ct) * 512 + lane * 8) = v;
    }
  }
}

// ---------------------------------------------------------------------------
// k_attn: grid (8, 96) = 768 blocks = EXACTLY 3 per CU (R5's 288-on-256
// imbalance was the 2x tail). 256 thr = 4 waves = 1 p-strip(48) x 4
// key-groups. Single register buffer (no dbuf) cuts per-wave VGPRs to
// ~150 -> __launch_bounds__(256,3): 3 waves/SIMD, and with 52 KB LDS all
// 3 blocks/CU are co-resident -- latency hiding moves from intra-wave
// prefetch (proved insufficient R1-R5) to TLP. Full-rate 16x16x32 PV via
// the key-permuted record pack. Strips of 48p reuse the existing 16-col
// thf group layout (group = strip*3 + pf).
// ---------------------------------------------------------------------------
__global__ __launch_bounds__(256, 3) void k_attn(
    const float* __restrict__ x, const _Float16* __restrict__ thf,
    const _Float16* __restrict__ rec, const float* __restrict__ ow,
    float* __restrict__ out) {
  const int strip = blockIdx.y >> 1;  // [0,48), 48 p each
  const int bt = SWIZ_BT(blockIdx.x, blockIdx.y);
  const int b = bt >> 3, t = bt & 7;
  const int tid = threadIdx.x;
  const int kg = tid >> 6, lane = tid & 63;
  const int quad = lane >> 4, l15 = lane & 15;

  __shared__ __align__(16) float exch[4 * 3 * 16 * 64];  // 48 KB
  __shared__ float exl[4 * 3 * 64];                      // 3 KB

  // theta B-frags for this strip's three 16-col groups
  h8 bth[3];
#pragma unroll
  for (int pf = 0; pf < 3; pf++)
    bth[pf] = *reinterpret_cast<const h8*>(
        thf + (((size_t)bt * 144 + strip * 3 + pf) * 64 + lane) * 8);

  const _Float16* recb =
      rec + ((size_t)bt * NKT + (size_t)kg * QKT) * 6144 + lane * 8;

  const f4 zero = {0.f, 0.f, 0.f, 0.f};
  f4 O[4][3];  // [ct][pf]: rows c=ct*16+quad*4+r, col p=strip*48+pf*16+l15
#pragma unroll
  for (int ct = 0; ct < 4; ct++)
#pragma unroll
    for (int pf = 0; pf < 3; pf++) O[ct][pf] = zero;
  float lsum[3] = {0.f, 0.f, 0.f};

  h8 buf[12];  // [0..3] phi A-frags, [4..11] x A-frags (g*4+ct)

#pragma unroll
  for (int i = 0; i < QKT; i++) {
    const _Float16* _p = recb + (size_t)i * 6144;
#pragma unroll
    for (int j = 0; j < 12; j++)
      buf[j] = *reinterpret_cast<const h8*>(_p + j * 512);

#pragma unroll
    for (int pf = 0; pf < 3; pf++) {
      f4 s[4];
#pragma unroll
      for (int nt = 0; nt < 4; nt++)
        s[nt] = __builtin_amdgcn_mfma_f32_16x16x32_f16(buf[nt], bth[pf], zero,
                                                       0, 0, 0);
#pragma unroll
      for (int g = 0; g < 2; g++) {
        h8 bw;
#pragma unroll
        for (int r = 0; r < 4; r++) {
          float w0 = EXP2(s[2 * g][r]);
          float w1 = EXP2(s[2 * g + 1][r]);
          lsum[pf] += w0 + w1;
          bw[r] = (_Float16)w0;
          bw[4 + r] = (_Float16)w1;
        }
#pragma unroll
        for (int ct = 0; ct < 4; ct++)
          O[ct][pf] = __builtin_amdgcn_mfma_f32_16x16x32_f16(
              buf[4 + g * 4 + ct], bw, O[ct][pf], 0, 0, 0);
      }
    }
  }

  // partial denominators: combine quad groups (p = pf*16+l15 fixed)
#pragma unroll
  for (int pf = 0; pf < 3; pf++) {
    lsum[pf] += __shfl_xor(lsum[pf], 16);
    lsum[pf] += __shfl_xor(lsum[pf], 32);
  }

  // all-to-all kg combine: publish everything; waves 0..2 finish pf=kg
#pragma unroll
  for (int pf = 0; pf < 3; pf++) {
#pragma unroll
    for (int ct = 0; ct < 4; ct++)
#pragma unroll
      for (int r = 0; r < 4; r++)
        exch[((kg * 3 + pf) * 16 + ct * 4 + r) * 64 + lane] = O[ct][pf][r];
    exl[(kg * 3 + pf) * 64 + lane] = lsum[pf];
  }
  __syncthreads();

  if (kg < 3) {
    float ls = 0.f;
#pragma unroll
    for (int src = 0; src < 4; src++) ls += exl[(src * 3 + kg) * 64 + lane];
    const float inv = 1.f / ls;

    // f in B-frag layout for out-proj: B[k=c=ct*16+quad*4+r][n=p=l15]
    h4 bf[4];
#pragma unroll
    for (int ct = 0; ct < 4; ct++)
#pragma unroll
      for (int r = 0; r < 4; r++) {
        float acc = 0.f;
#pragma unroll
        for (int src = 0; src < 4; src++)
          acc += exch[((src * 3 + kg) * 16 + ct * 4 + r) * 64 + lane];
        bf[ct][r] = (_Float16)(acc * inv);
      }

    f4 D3[4] = {zero, zero, zero, zero};
#pragma unroll
    for (int mt = 0; mt < 4; mt++)
#pragma unroll
      for (int ct = 0; ct < 4; ct++) {
        const float* wrow =
            ow + (size_t)(mt * 16 + l15) * CC + ct * 16 + quad * 4;
        float4 u = *reinterpret_cast<const float4*>(wrow);
        h4 aw = {(_Float16)u.x, (_Float16)u.y, (_Float16)u.z, (_Float16)u.w};
        D3[mt] =
            __builtin_amdgcn_mfma_f32_16x16x16f16(aw, bf[ct], D3[mt], 0, 0, 0);
      }

    // stores with fp32 residual; wave kg owns p block strip*48 + kg*16
    const int p0 = strip * 48 + kg * 16 + l15;
#pragma unroll
    for (int mt = 0; mt < 4; mt++)
#pragma unroll
      for (int r = 0; r < 4; r++) {
        const int o = mt * 16 + quad * 4 + r;
        const size_t base = ((size_t)(b * CC + o) * TT + t) * PP + p0;
        out[base] = D3[mt][r] + x[base];
      }
  }
}

extern "C" void kernel_launch(void* const* d_in, const int* in_sizes, int n_in,
                              void* d_out, int out_size, void* d_ws,
                              size_t ws_size, hipStream_t stream) {
  (void)in_sizes; (void)n_in; (void)out_size; (void)ws_size;
  const float* x = (const float*)d_in[0];
  const float* tw = (const float*)d_in[1];
  const float* pw = (const float*)d_in[2];
  const float* ow = (const float*)d_in[3];
  float* out = (float*)d_out;

  _Float16* thf = (_Float16*)d_ws;                      // 2.25 MB
  _Float16* rec = thf + (size_t)BT * NKT * 4 * 64 * 8;  // 7.08 MB

  k_prep<<<dim3(8, 72), 256, 0, stream>>>(x, tw, pw, thf, rec);
  k_attn<<<dim3(8, 96), 256, 0, stream>>>(x, thf, rec, ow, out);
}